// Round 11
// baseline (344.704 us; speedup 1.0000x reference)
//
#include <hip/hip_runtime.h>
#include <math.h>

// Problem constants
#define DIMC   512
#define HEADS  8
#define SLOTS  112
#define HD     64          // DIMC/HEADS
#define NROWS  16384       // B*S = 32*512
#define RADIUSF 16.0f

typedef short short8 __attribute__((ext_vector_type(8)));
typedef unsigned short ushort8 __attribute__((ext_vector_type(8)));
typedef float f32x4  __attribute__((ext_vector_type(4)));

__device__ __forceinline__ unsigned short f2bf(float f)
{
    unsigned u = __float_as_uint(f);
    unsigned r = (u + 0x7FFFu + ((u >> 16) & 1u)) >> 16;   // RNE
    return (unsigned short)r;
}
__device__ __forceinline__ float bf2f(unsigned short h)
{
    return __uint_as_float((unsigned)h << 16);
}

// Async global->LDS 16B/lane. LDS dest is wave-uniform base + lane*16.
__device__ __forceinline__ void gl16(const void* g, void* lds_wave_base)
{
    __builtin_amdgcn_global_load_lds(
        (const __attribute__((address_space(1))) unsigned int*)g,
        (__attribute__((address_space(3))) unsigned int*)lds_wave_base,
        16, 0, 0);
}

// ---------------------------------------------------------------------------
// DPP-based wave reductions (validated rounds 2-8). VALU-only, no LDS pipe.
// ---------------------------------------------------------------------------
#define DPP_ADD(x, ctrl, rmask)                                               \
    (x) += __int_as_float(__builtin_amdgcn_update_dpp(                        \
               0, __float_as_int(x), (ctrl), (rmask), 0xf, true))

__device__ __forceinline__ float wsum64(float x)
{
    DPP_ADD(x, 0x111, 0xf);
    DPP_ADD(x, 0x112, 0xf);
    DPP_ADD(x, 0x114, 0xf);
    DPP_ADD(x, 0x118, 0xf);
    DPP_ADD(x, 0x142, 0xa);
    DPP_ADD(x, 0x143, 0xc);
    return __int_as_float(__builtin_amdgcn_readlane(__float_as_int(x), 63));
}

__device__ __forceinline__ void wsum64_4(float& a, float& b, float& c, float& d)
{
    DPP_ADD(a, 0x111, 0xf); DPP_ADD(b, 0x111, 0xf); DPP_ADD(c, 0x111, 0xf); DPP_ADD(d, 0x111, 0xf);
    DPP_ADD(a, 0x112, 0xf); DPP_ADD(b, 0x112, 0xf); DPP_ADD(c, 0x112, 0xf); DPP_ADD(d, 0x112, 0xf);
    DPP_ADD(a, 0x114, 0xf); DPP_ADD(b, 0x114, 0xf); DPP_ADD(c, 0x114, 0xf); DPP_ADD(d, 0x114, 0xf);
    DPP_ADD(a, 0x118, 0xf); DPP_ADD(b, 0x118, 0xf); DPP_ADD(c, 0x118, 0xf); DPP_ADD(d, 0x118, 0xf);
    DPP_ADD(a, 0x142, 0xa); DPP_ADD(b, 0x142, 0xa); DPP_ADD(c, 0x142, 0xa); DPP_ADD(d, 0x142, 0xa);
    DPP_ADD(a, 0x143, 0xc); DPP_ADD(b, 0x143, 0xc); DPP_ADD(c, 0x143, 0xc); DPP_ADD(d, 0x143, 0xc);
    a = __int_as_float(__builtin_amdgcn_readlane(__float_as_int(a), 63));
    b = __int_as_float(__builtin_amdgcn_readlane(__float_as_int(b), 63));
    c = __int_as_float(__builtin_amdgcn_readlane(__float_as_int(c), 63));
    d = __int_as_float(__builtin_amdgcn_readlane(__float_as_int(d), 63));
}

// ---------------------------------------------------------------------------
// bf16 MFMA GEMM: C(MxN fp32) / Cb(MxN bf16) = A(MxK bf16) @ B(NxK bf16)^T
// (+ bias[col]). 128x128 tile, BK=32, gl16 staging (validated round 5/6).
// ---------------------------------------------------------------------------
__global__ __launch_bounds__(256)
void gemm_bf16(const short* __restrict__ A, int lda,
               const short* __restrict__ B, int ldb,
               float* __restrict__ C, unsigned short* __restrict__ Cb,
               int ldc, int K, const float* __restrict__ bias, int Nvalid,
               int aZ, int bZ, int cZ)
{
    __shared__ short As[128 * 32];
    __shared__ short Bs[128 * 32];
    A += (size_t)blockIdx.z * aZ;
    B += (size_t)blockIdx.z * bZ;
    const size_t czoff = (size_t)blockIdx.z * cZ;
    const int tid  = threadIdx.x;
    const int wave = tid >> 6;
    const int lane = tid & 63;
    const int m0 = blockIdx.y * 128;
    const int n0 = blockIdx.x * 128;
    const int wm = (wave >> 1) * 64;
    const int wn = (wave & 1) * 64;

    const int srow = tid >> 2;
    const int schk = (tid & 3) * 8;

    const int fr = lane & 15;
    const int fq = (lane >> 4) * 8;

    f32x4 acc[4][4] = {};

    const short* Ag = A + (size_t)(m0 + srow) * lda + schk;
    const short* Bg = B + (size_t)(n0 + srow) * ldb + schk;

    short* asL = As + wave * 512;
    short* asU = As + 2048 + wave * 512;
    short* bsL = Bs + wave * 512;
    short* bsU = Bs + 2048 + wave * 512;

    for (int k0 = 0; k0 < K; k0 += 32) {
        gl16(Ag, asL);
        gl16(Ag + (size_t)64 * lda, asU);
        gl16(Bg, bsL);
        gl16(Bg + (size_t)64 * ldb, bsU);
        Ag += 32; Bg += 32;
        __syncthreads();
        short8 af[4], bf[4];
        #pragma unroll
        for (int i = 0; i < 4; ++i)
            af[i] = *(const short8*)&As[(wm + i * 16 + fr) * 32 + fq];
        #pragma unroll
        for (int j = 0; j < 4; ++j)
            bf[j] = *(const short8*)&Bs[(wn + j * 16 + fr) * 32 + fq];
        #pragma unroll
        for (int i = 0; i < 4; ++i)
            #pragma unroll
            for (int j = 0; j < 4; ++j)
                acc[i][j] = __builtin_amdgcn_mfma_f32_16x16x32_bf16(
                    af[i], bf[j], acc[i][j], 0, 0, 0);
        __syncthreads();
    }

    const int cr = (lane >> 4) * 4;
    const int cc = lane & 15;
    #pragma unroll
    for (int i = 0; i < 4; ++i) {
        const int grow = m0 + wm + i * 16 + cr;
        #pragma unroll
        for (int j = 0; j < 4; ++j) {
            const int gcol = n0 + wn + j * 16 + cc;
            if (gcol < Nvalid) {
                const float bb = bias ? bias[gcol] : 0.f;
                const size_t base = czoff + (size_t)grow * ldc + gcol;
                #pragma unroll
                for (int r = 0; r < 4; ++r) {
                    const float val = acc[i][j][r] + bb;
                    if (C)  C[base + (size_t)r * ldc]  = val;
                    if (Cb) Cb[base + (size_t)r * ldc] = f2bf(val);
                }
            }
        }
    }
}

// ---------------------------------------------------------------------------
// Fused GEMM + in-kernel row-l2norm + row-softmax (validated round 6).
// ---------------------------------------------------------------------------
__global__ __launch_bounds__(256)
void gemm_softmax(const short* __restrict__ A, int lda, int aZ,
                  const short* __restrict__ B, int ldb, int bZ,
                  int K,
                  unsigned short* __restrict__ Ob, int ldo, int oPerZ, int padN)
{
    __shared__ short As[128 * 32];
    __shared__ short Bs[128 * 32];
    __shared__ float P[128][113];
    __shared__ float hinvS[128];
    A += (size_t)blockIdx.z * aZ;
    B += (size_t)blockIdx.z * bZ;
    const int tid  = threadIdx.x;
    const int wave = tid >> 6;
    const int lane = tid & 63;
    const int m0 = blockIdx.y * 128;
    const int wm = (wave >> 1) * 64;
    const int wn = (wave & 1) * 64;
    const int srow = tid >> 2;
    const int schk = (tid & 3) * 8;
    const int fr = lane & 15;
    const int fq = (lane >> 4) * 8;

    f32x4 acc[4][4] = {};
    float ss[4] = {0.f, 0.f, 0.f, 0.f};

    const short* Ag = A + (size_t)(m0 + srow) * lda + schk;
    const short* Bg = B + (size_t)srow * ldb + schk;

    short* asL = As + wave * 512;
    short* asU = As + 2048 + wave * 512;
    short* bsL = Bs + wave * 512;
    short* bsU = Bs + 2048 + wave * 512;

    for (int k0 = 0; k0 < K; k0 += 32) {
        gl16(Ag, asL);
        gl16(Ag + (size_t)64 * lda, asU);
        gl16(Bg, bsL);
        gl16(Bg + (size_t)64 * ldb, bsU);
        Ag += 32; Bg += 32;
        __syncthreads();
        short8 af[4], bf[4];
        #pragma unroll
        for (int i = 0; i < 4; ++i)
            af[i] = *(const short8*)&As[(wm + i * 16 + fr) * 32 + fq];
        #pragma unroll
        for (int j = 0; j < 4; ++j)
            bf[j] = *(const short8*)&Bs[(wn + j * 16 + fr) * 32 + fq];
        #pragma unroll
        for (int i = 0; i < 4; ++i)
            #pragma unroll
            for (int e = 0; e < 8; ++e) {
                const float f = bf2f((unsigned short)af[i][e]);
                ss[i] += f * f;
            }
        #pragma unroll
        for (int i = 0; i < 4; ++i)
            #pragma unroll
            for (int j = 0; j < 4; ++j)
                acc[i][j] = __builtin_amdgcn_mfma_f32_16x16x32_bf16(
                    af[i], bf[j], acc[i][j], 0, 0, 0);
        __syncthreads();
    }

    #pragma unroll
    for (int i = 0; i < 4; ++i) {
        ss[i] += __shfl_xor(ss[i], 16, 64);
        ss[i] += __shfl_xor(ss[i], 32, 64);
    }
    if (lane < 16) {
        #pragma unroll
        for (int i = 0; i < 4; ++i)
            hinvS[wm + i * 16 + lane] = 1.f / fmaxf(sqrtf(ss[i]), 1e-12f);
    }

    const int cr = (lane >> 4) * 4;
    const int cc = lane & 15;
    #pragma unroll
    for (int i = 0; i < 4; ++i) {
        const int prow = wm + i * 16 + cr;
        #pragma unroll
        for (int j = 0; j < 4; ++j) {
            const int pcol = wn + j * 16 + cc;
            if (pcol < SLOTS) {
                #pragma unroll
                for (int r = 0; r < 4; ++r)
                    P[prow + r][pcol] = acc[i][j][r];
            }
        }
    }
    __syncthreads();

    const int rowt = tid >> 1;
    const int half = tid & 1;
    const int k0 = half * 56;
    const int rr = m0 + rowt;
    const float s = RADIUSF * hinvS[rowt];
    float mx = -1e30f;
    for (int k = k0; k < k0 + 56; ++k) mx = fmaxf(mx, P[rowt][k]);
    mx = fmaxf(mx, __shfl_xor(mx, 1, 64));
    float sum = 0.f;
    for (int k = k0; k < k0 + 56; ++k) {
        const float e = __expf(s * (P[rowt][k] - mx));
        P[rowt][k] = e;
        sum += e;
    }
    sum += __shfl_xor(sum, 1, 64);
    const float inv = 1.f / sum;
    unsigned short* orow = Ob + (size_t)rr * ldo + (size_t)blockIdx.z * oPerZ;
    for (int k = k0; k < k0 + 56; ++k) orow[k] = f2bf(P[rowt][k] * inv);
    if (half == 1)
        for (int k = SLOTS; k < padN; ++k) orow[k] = 0;
}

// ---------------------------------------------------------------------------
// Round-13 gemm_vir_te (resubmitted round-14 after infra flake): 64x512 tile,
// 1024 threads = 16 waves. Round-9 post-mortem: M=64 @ 512 thr/85KB LDS
// collapsed to 2 waves/SIMD — occupancy loss beat the L2-traffic halving.
// Fix both: 16 waves/block restores 4 waves/SIMD at 1 block/CU, and LDS
// shrinks to 74 KB by aliasing the LN-param block into Bs0 (only read
// after the GEMM loop). Wave (s,h) owns rows s*16..+15 x cols h*128..+127
// (acc = 8 frags = 32 VGPR). Register-resident LN epilogue (refcheck'd
// round 9), reduced across 4 col-quarters via red[64][4].
// B-panel traffic: 235 MB (half of round-8's 470 MB).
// ---------------------------------------------------------------------------
__global__ __launch_bounds__(1024, 4)
void gemm_vir_te(const short* __restrict__ A, int lda,
                 const short* __restrict__ B, int ldb, int K,
                 const float* __restrict__ bias, const float* __restrict__ query,
                 const float* __restrict__ g1, const float* __restrict__ b1,
                 const float* __restrict__ g2, const float* __restrict__ b2,
                 float* __restrict__ out_te)
{
    __shared__ short As0[64 * 32];         // 4 KB (K-chunk 0)
    __shared__ short As1[64 * 32];         // 4 KB (K-chunk 1)
    __shared__ short Bs0[512 * 32];        // 32 KB
    __shared__ short Bs1[512 * 32];        // 32 KB
    __shared__ float red1[256], red2[256]; // [64 rows][4 quarters], 2 KB
    float* parm = (float*)Bs0;             // aliased post-loop: bl,g2,b2,g1,b1

    const int tid  = threadIdx.x;
    const int wave = tid >> 6;             // 0..15
    const int lane = tid & 63;
    const int m0 = blockIdx.x * 64;
    const int s = wave >> 2;               // row stripe 0..3 (16 rows)
    const int h = wave & 3;                // col quarter 0..3 (128 cols)
    const int fr = lane & 15;
    const int fq = (lane >> 4) * 8;

    f32x4 acc[8] = {};

    const int lrow = lane >> 2;
    const int lchk = (lane & 3) * 8;

    for (int k0 = 0; k0 < K; k0 += 64) {
        if (wave < 4)
            gl16(A + (size_t)(m0 + wave * 16 + lrow) * lda + k0 + lchk,
                 As0 + wave * 512);
        else if (wave < 8)
            gl16(A + (size_t)(m0 + (wave - 4) * 16 + lrow) * lda + k0 + 32 + lchk,
                 As1 + (wave - 4) * 512);
        #pragma unroll
        for (int g = 0; g < 2; ++g) {
            const size_t br = (size_t)(wave * 32 + g * 16 + lrow);
            gl16(B + br * ldb + k0 + lchk,      Bs0 + (wave * 32 + g * 16) * 32);
            gl16(B + br * ldb + k0 + 32 + lchk, Bs1 + (wave * 32 + g * 16) * 32);
        }
        __syncthreads();
        const short8 af0 = *(const short8*)&As0[(s * 16 + fr) * 32 + fq];
        const short8 af1 = *(const short8*)&As1[(s * 16 + fr) * 32 + fq];
        #pragma unroll
        for (int c = 0; c < 8; ++c) {
            const short8 bf0 = *(const short8*)&Bs0[(h * 128 + c * 16 + fr) * 32 + fq];
            acc[c] = __builtin_amdgcn_mfma_f32_16x16x32_bf16(af0, bf0, acc[c], 0, 0, 0);
            const short8 bf1 = *(const short8*)&Bs1[(h * 128 + c * 16 + fr) * 32 + fq];
            acc[c] = __builtin_amdgcn_mfma_f32_16x16x32_bf16(af1, bf1, acc[c], 0, 0, 0);
        }
        __syncthreads();
    }

    // LN params into LDS aliased over Bs0 (loop done, barrier passed).
    if (tid < 512) {
        parm[tid]        = bias[tid];
        parm[512 + tid]  = g2[tid];
        parm[1024 + tid] = b2[tid];
    } else {
        const int t = tid - 512;
        parm[1536 + t] = g1[t];
        parm[2048 + t] = b1[t];
    }
    __syncthreads();

    // ----- register-resident epilogue (structure refcheck'd round 9) -----
    const int cc = lane & 15;              // col within fragment
    const int cr = (lane >> 4) * 4;        // row group base within stripe
    const int rowb = s * 16 + cr;          // local row base (4 rows)

    // Phase A: sums of x = acc + bl over 512 cols
    float s1[4] = {0.f, 0.f, 0.f, 0.f}, s2[4] = {0.f, 0.f, 0.f, 0.f};
    #pragma unroll
    for (int c = 0; c < 8; ++c) {
        const float blc = parm[h * 128 + c * 16 + cc];
        #pragma unroll
        for (int r = 0; r < 4; ++r) {
            const float x = acc[c][r] + blc;
            s1[r] += x;
            s2[r] += x * x;
        }
    }
    #pragma unroll
    for (int k = 1; k < 16; k <<= 1)
        #pragma unroll
        for (int r = 0; r < 4; ++r) {
            s1[r] += __shfl_xor(s1[r], k, 16);
            s2[r] += __shfl_xor(s2[r], k, 16);
        }
    if (cc == 0)
        #pragma unroll
        for (int r = 0; r < 4; ++r) {
            red1[(rowb + r) * 4 + h] = s1[r];
            red2[(rowb + r) * 4 + h] = s2[r];
        }
    __syncthreads();
    float mu[4], rs[4];
    #pragma unroll
    for (int r = 0; r < 4; ++r) {
        const float t1 = red1[(rowb + r) * 4] + red1[(rowb + r) * 4 + 1]
                       + red1[(rowb + r) * 4 + 2] + red1[(rowb + r) * 4 + 3];
        const float t2 = red2[(rowb + r) * 4] + red2[(rowb + r) * 4 + 1]
                       + red2[(rowb + r) * 4 + 2] + red2[(rowb + r) * 4 + 3];
        mu[r] = t1 * (1.f / DIMC);
        const float var = t2 * (1.f / DIMC) - mu[r] * mu[r];
        rs[r] = rsqrtf(var + 1e-5f);
    }
    __syncthreads();   // red reuse below

    // Phase B: y = q + LN1(x); sums of y
    float t1[4] = {0.f, 0.f, 0.f, 0.f}, t2[4] = {0.f, 0.f, 0.f, 0.f};
    #pragma unroll
    for (int c = 0; c < 8; ++c) {
        const int col = h * 128 + c * 16 + cc;
        const float blc = parm[col];
        const float g2c = parm[512 + col];
        const float b2c = parm[1024 + col];
        #pragma unroll
        for (int r = 0; r < 4; ++r) {
            const float x = acc[c][r] + blc;
            const float qv = query[(size_t)(m0 + rowb + r) * DIMC + col];
            const float y = qv + (x - mu[r]) * rs[r] * g2c + b2c;
            t1[r] += y;
            t2[r] += y * y;
        }
    }
    #pragma unroll
    for (int k = 1; k < 16; k <<= 1)
        #pragma unroll
        for (int r = 0; r < 4; ++r) {
            t1[r] += __shfl_xor(t1[r], k, 16);
            t2[r] += __shfl_xor(t2[r], k, 16);
        }
    if (cc == 0)
        #pragma unroll
        for (int r = 0; r < 4; ++r) {
            red1[(rowb + r) * 4 + h] = t1[r];
            red2[(rowb + r) * 4 + h] = t2[r];
        }
    __syncthreads();
    float mu2[4], rs2[4];
    #pragma unroll
    for (int r = 0; r < 4; ++r) {
        const float u1 = red1[(rowb + r) * 4] + red1[(rowb + r) * 4 + 1]
                       + red1[(rowb + r) * 4 + 2] + red1[(rowb + r) * 4 + 3];
        const float u2 = red2[(rowb + r) * 4] + red2[(rowb + r) * 4 + 1]
                       + red2[(rowb + r) * 4 + 2] + red2[(rowb + r) * 4 + 3];
        mu2[r] = u1 * (1.f / DIMC);
        const float var = u2 * (1.f / DIMC) - mu2[r] * mu2[r];
        rs2[r] = rsqrtf(var + 1e-5f);
    }

    // Phase C: out = LN2(y) (q reload is L2-hot)
    #pragma unroll
    for (int c = 0; c < 8; ++c) {
        const int col = h * 128 + c * 16 + cc;
        const float blc = parm[col];
        const float g2c = parm[512 + col];
        const float b2c = parm[1024 + col];
        const float g1c = parm[1536 + col];
        const float b1c = parm[2048 + col];
        #pragma unroll
        for (int r = 0; r < 4; ++r) {
            const float x = acc[c][r] + blc;
            const float qv = query[(size_t)(m0 + rowb + r) * DIMC + col];
            const float y = qv + (x - mu[r]) * rs[r] * g2c + b2c;
            out_te[(size_t)(m0 + rowb + r) * DIMC + col] =
                (y - mu2[r]) * rs2[r] * g1c + b1c;
        }
    }
}

// ---------------------------------------------------------------------------
// Round-11 fused GEMM (32x512 tile) + LN epilogue — kept for the aud path
// (K=128: GEMM is 2 iterations; the epilogue is HBM-bound on value+query).
// ---------------------------------------------------------------------------
#define FUSED_LDS_DECL                                                        \
    __shared__ float U[17408];  /* 69632 B: staging (68 KB) ∪ P (64.5 KB) */  \
    float* P = U;                                                             \
    short* As0 = (short*)U;          /* [32][32] chunk 0 */                   \
    short* As1 = As0 + 1024;         /* [32][32] chunk 1 */                   \
    short* Bs0 = As1 + 1024;         /* [512][32] chunk 0 */                  \
    short* Bs1 = Bs0 + 16384;        /* [512][32] chunk 1 */

#define FUSED_GEMM_CORE(Aptr, lda, Bptr, ldb, K)                              \
    f32x4 acc[2][4] = {};                                                     \
    {                                                                         \
        const int lrow = lane >> 2;                                           \
        const int lchk = (lane & 3) * 8;                                      \
        for (int k0 = 0; k0 < (K); k0 += 64) {                                \
            if (wave < 2)                                                     \
                gl16((Aptr) + (size_t)(m0 + wave * 16 + lrow) * (lda) + k0 + lchk, \
                     As0 + wave * 512);                                       \
            else if (wave < 4)                                                \
                gl16((Aptr) + (size_t)(m0 + (wave - 2) * 16 + lrow) * (lda) + k0 + 32 + lchk, \
                     As1 + (wave - 2) * 512);                                 \
            _Pragma("unroll")                                                 \
            for (int s = 0; s < 4; ++s) {                                     \
                const size_t brow = (size_t)(wave * 64 + s * 16 + lrow);      \
                gl16((Bptr) + brow * (ldb) + k0 + lchk,                       \
                     Bs0 + (wave * 64 + s * 16) * 32);                        \
                gl16((Bptr) + brow * (ldb) + k0 + 32 + lchk,                  \
                     Bs1 + (wave * 64 + s * 16) * 32);                        \
            }                                                                 \
            __syncthreads();                                                  \
            short8 af0[2], af1[2], bf0[4], bf1[4];                            \
            _Pragma("unroll")                                                 \
            for (int i = 0; i < 2; ++i) {                                     \
                af0[i] = *(const short8*)&As0[(i * 16 + fr) * 32 + fq];       \
                af1[i] = *(const short8*)&As1[(i * 16 + fr) * 32 + fq];       \
            }                                                                 \
            _Pragma("unroll")                                                 \
            for (int c = 0; c < 4; ++c) {                                     \
                bf0[c] = *(const short8*)&Bs0[(wave * 64 + c * 16 + fr) * 32 + fq]; \
                bf1[c] = *(const short8*)&Bs1[(wave * 64 + c * 16 + fr) * 32 + fq]; \
            }                                                                 \
            _Pragma("unroll")                                                 \
            for (int i = 0; i < 2; ++i)                                       \
                _Pragma("unroll")                                             \
                for (int c = 0; c < 4; ++c) {                                 \
                    acc[i][c] = __builtin_amdgcn_mfma_f32_16x16x32_bf16(      \
                        af0[i], bf0[c], acc[i][c], 0, 0, 0);                  \
                    acc[i][c] = __builtin_amdgcn_mfma_f32_16x16x32_bf16(      \
                        af1[i], bf1[c], acc[i][c], 0, 0, 0);                  \
                }                                                             \
            __syncthreads();                                                  \
        }                                                                     \
    }                                                                         \
    {                                                                         \
        const int cr = (lane >> 4) * 4;                                       \
        const int cc = lane & 15;                                             \
        _Pragma("unroll")                                                     \
        for (int i = 0; i < 2; ++i)                                           \
            _Pragma("unroll")                                                 \
            for (int c = 0; c < 4; ++c) {                                     \
                const int col = wave * 64 + c * 16 + cc;                      \
                _Pragma("unroll")                                             \
                for (int r = 0; r < 4; ++r)                                   \
                    P[(i * 16 + cr + r) * 516 + col] = acc[i][c][r];          \
            }                                                                 \
    }                                                                         \
    __syncthreads();

// aud path: a = A@B^T -> cos/recon vs value -> LN(g3,b3) -> +query ->
// LN(g1,b1) -> out_tr (+ one recon atomic per block; 32 | 512).
__global__ __launch_bounds__(512, 4)
void gemm_aud_tr(const short* __restrict__ A, int lda,
                 const short* __restrict__ B, int ldb, int K,
                 const float* __restrict__ value, const float* __restrict__ query,
                 const float* __restrict__ g1, const float* __restrict__ b1,
                 const float* __restrict__ g3, const float* __restrict__ b3,
                 float* __restrict__ out_tr, float* __restrict__ recon)
{
    FUSED_LDS_DECL
    __shared__ float red[8];
    const int tid = threadIdx.x;
    const int wave = tid >> 6;
    const int lane = tid & 63;
    const int m0 = blockIdx.x * 32;
    const int fr = lane & 15;
    const int fq = (lane >> 4) * 8;

    FUSED_GEMM_CORE(A, lda, B, ldb, K)

    const int c0 = lane * 8;
    float gg3[8], bb3[8], gg1[8], bb1[8];
    *(f32x4*)&gg3[0] = *(const f32x4*)(g3 + c0);
    *(f32x4*)&gg3[4] = *(const f32x4*)(g3 + c0 + 4);
    *(f32x4*)&bb3[0] = *(const f32x4*)(b3 + c0);
    *(f32x4*)&bb3[4] = *(const f32x4*)(b3 + c0 + 4);
    *(f32x4*)&gg1[0] = *(const f32x4*)(g1 + c0);
    *(f32x4*)&gg1[4] = *(const f32x4*)(g1 + c0 + 4);
    *(f32x4*)&bb1[0] = *(const f32x4*)(b1 + c0);
    *(f32x4*)&bb1[4] = *(const f32x4*)(b1 + c0 + 4);

    float rloc = 0.f;
    for (int rp = 0; rp < 2; ++rp) {
        const int lr0 = wave * 4 + rp * 2;
        float a[2][8], v[2][8], q[2][8];
        #pragma unroll
        for (int p = 0; p < 2; ++p) {
            *(f32x4*)&a[p][0] = *(const f32x4*)&P[(lr0 + p) * 516 + c0];
            *(f32x4*)&a[p][4] = *(const f32x4*)&P[(lr0 + p) * 516 + c0 + 4];
            const size_t gbase = (size_t)(m0 + lr0 + p) * DIMC + c0;
            *(f32x4*)&v[p][0] = *(const f32x4*)(value + gbase);
            *(f32x4*)&v[p][4] = *(const f32x4*)(value + gbase + 4);
            *(f32x4*)&q[p][0] = *(const f32x4*)(query + gbase);
            *(f32x4*)&q[p][4] = *(const f32x4*)(query + gbase + 4);
        }
        float dot[2] = {0.f, 0.f}, na[2] = {0.f, 0.f};
        float nv[2] = {0.f, 0.f}, s1[2] = {0.f, 0.f};
        #pragma unroll
        for (int p = 0; p < 2; ++p)
            #pragma unroll
            for (int j = 0; j < 8; ++j) {
                dot[p] += a[p][j] * v[p][j];
                na[p]  += a[p][j] * a[p][j];
                nv[p]  += v[p][j] * v[p][j];
                s1[p]  += a[p][j];
            }
        wsum64_4(dot[0], na[0], nv[0], s1[0]);
        wsum64_4(dot[1], na[1], nv[1], s1[1]);

        #pragma unroll
        for (int p = 0; p < 2; ++p) {
            const float cosv = dot[p] / fmaxf(sqrtf(na[p]) * sqrtf(nv[p]), 1e-8f);
            rloc += fabsf(1.f - cosv);
        }

        float y[2][8];
        float t1[2] = {0.f, 0.f}, t2[2] = {0.f, 0.f};
        #pragma unroll
        for (int p = 0; p < 2; ++p) {
            const float mu = s1[p] * (1.f / DIMC);
            const float var = na[p] * (1.f / DIMC) - mu * mu;   // na == sum(a^2)
            const float rstd = rsqrtf(var + 1e-5f);
            #pragma unroll
            for (int j = 0; j < 8; ++j) {
                const float w = (a[p][j] - mu) * rstd * gg3[j] + bb3[j];
                y[p][j] = q[p][j] + w;
                t1[p] += y[p][j];
                t2[p] += y[p][j] * y[p][j];
            }
        }
        wsum64_4(t1[0], t2[0], t1[1], t2[1]);

        #pragma unroll
        for (int p = 0; p < 2; ++p) {
            const float mu = t1[p] * (1.f / DIMC);
            const float var = t2[p] * (1.f / DIMC) - mu * mu;
            const float rstd = rsqrtf(var + 1e-5f);
            float o[8];
            #pragma unroll
            for (int j = 0; j < 8; ++j)
                o[j] = (y[p][j] - mu) * rstd * gg1[j] + bb1[j];
            const size_t gbase = (size_t)(m0 + lr0 + p) * DIMC + c0;
            *(float4*)(out_tr + gbase)     = make_float4(o[0], o[1], o[2], o[3]);
            *(float4*)(out_tr + gbase + 4) = make_float4(o[4], o[5], o[6], o[7]);
        }
    }

    if (lane == 0) red[wave] = rloc;
    __syncthreads();
    if (tid == 0)
        atomicAdd(&recon[m0 >> 9], red[0] + red[1] + red[2] + red[3]
                                 + red[4] + red[5] + red[6] + red[7]);
}

// ---------------------------------------------------------------------------
// Small helpers (all validated round 6)
// ---------------------------------------------------------------------------
__device__ __forceinline__ float block_sum_256(float v, float* red)
{
    #pragma unroll
    for (int off = 32; off; off >>= 1) v += __shfl_down(v, off, 64);
    const int lane = threadIdx.x & 63, wid = threadIdx.x >> 6;
    __syncthreads();
    if (lane == 0) red[wid] = v;
    __syncthreads();
    return red[0] + red[1] + red[2] + red[3];
}

__global__ void conv_all(const float* __restrict__ q, const float* __restrict__ v,
                         const float* __restrict__ Wq, const float* __restrict__ Wv,
                         const float* __restrict__ Wl, const float* __restrict__ vm,
                         unsigned short* __restrict__ qbf, unsigned short* __restrict__ vbf,
                         unsigned short* __restrict__ wqbf, unsigned short* __restrict__ wvbf,
                         unsigned short* __restrict__ wlbf, unsigned short* __restrict__ vmbf)
{
    const int i = blockIdx.x * blockDim.x + threadIdx.x;   // float4-unit index
    const float* src;
    unsigned short* dst;
    int off;
    if (i < 2097152)      { src = q;  dst = qbf;  off = i; }
    else if (i < 4194304) { src = v;  dst = vbf;  off = i - 2097152; }
    else if (i < 4259840) { src = Wq; dst = wqbf; off = i - 4194304; }
    else if (i < 4325376) { src = Wv; dst = wvbf; off = i - 4259840; }
    else if (i < 4849664) { src = Wl; dst = wlbf; off = i - 4325376; }
    else if (i < 4864000) { src = vm; dst = vmbf; off = i - 4849664; }
    else {                 // zero vmbf pad rows 112..127 (8192 bf16)
        const int j = i - 4864000;   // 0..2047
        *(ushort4*)(vmbf + 57344 + (size_t)j * 4) = make_ushort4(0, 0, 0, 0);
        return;
    }
    const float4 x = *(const float4*)(src + (size_t)off * 4);
    ushort4 o;
    o.x = f2bf(x.x); o.y = f2bf(x.y); o.z = f2bf(x.z); o.w = f2bf(x.w);
    *(ushort4*)(dst + (size_t)off * 4) = o;
}

__global__ void prep_key_norm(const float* __restrict__ km,
                              unsigned short* __restrict__ knb,
                              float* __restrict__ outrc)
{
    const int row = blockIdx.x;         // h*128+s
    const int h = row >> 7, s = row & 127;
    const int lane = threadIdx.x;       // 64 threads
    if (row == 0 && lane < 33) outrc[lane] = 0.f;
    const float v = (s < SLOTS) ? km[(size_t)(h * SLOTS + s) * HD + lane] : 0.f;
    const float ssum = wsum64(v * v);
    const float inv = 1.f / fmaxf(sqrtf(ssum), 1e-12f);
    knb[(size_t)row * HD + lane] = f2bf(v * inv);
}

__global__ void prep_value_norm(const float* __restrict__ vm,
                                float* __restrict__ vn,
                                unsigned short* __restrict__ vnb,
                                unsigned short* __restrict__ vmTb)
{
    const int row = blockIdx.x;        // 0..175
    const int tid = threadIdx.x;       // 256
    if (row >= 112) {
        const int idx = (row - 112) * 256 + tid;   // 0..16383
        if (idx < 8192) {
            vmTb[(size_t)(idx >> 4) * 128 + 112 + (idx & 15)] = 0;
        } else {
            const int j = idx - 8192;
            vnb[(size_t)(112 + (j >> 9)) * 512 + (j & 511)] = 0;
        }
        return;
    }
    __shared__ float red[4];
    const float v0 = vm[(size_t)row * DIMC + tid];
    const float v1 = vm[(size_t)row * DIMC + 256 + tid];
    const float tot = block_sum_256(v0 * v0 + v1 * v1, red);
    const float inv = 1.f / fmaxf(sqrtf(tot), 1e-12f);
    vn[(size_t)row * DIMC + tid]        = v0 * inv;
    vn[(size_t)row * DIMC + 256 + tid]  = v1 * inv;
    vnb[(size_t)row * DIMC + tid]       = f2bf(v0 * inv);
    vnb[(size_t)row * DIMC + 256 + tid] = f2bf(v1 * inv);
    vmTb[(size_t)tid * 128 + row]         = f2bf(v0);
    vmTb[(size_t)(256 + tid) * 128 + row] = f2bf(v1);
}

__global__ void contrastive_kernel(const float* __restrict__ vn, float* __restrict__ outc)
{
    __shared__ float vni[DIMC];
    __shared__ float red[2];
    const int i = blockIdx.x, tid = threadIdx.x;   // 128 threads
    for (int d = tid; d < DIMC; d += 128) vni[d] = vn[(size_t)i * DIMC + d];
    __syncthreads();
    float t = 0.f;
    if (tid < SLOTS) {
        const float* r = vn + (size_t)tid * DIMC;
        float dot = 0.f;
        for (int d = 0; d < DIMC; ++d) dot += vni[d] * r[d];
        const float delta = (tid == i) ? 1.f : 0.f;
        t = fabsf(delta - dot);
    }
    #pragma unroll
    for (int off = 32; off; off >>= 1) t += __shfl_down(t, off, 64);
    if ((tid & 63) == 0) red[tid >> 6] = t;
    __syncthreads();
    if (tid == 0) atomicAdd(outc, 0.5f * (red[0] + red[1]));
}

// ---------------------------------------------------------------------------
// Launch
// ---------------------------------------------------------------------------
extern "C" void kernel_launch(void* const* d_in, const int* in_sizes, int n_in,
                              void* d_out, int out_size, void* d_ws, size_t ws_size,
                              hipStream_t stream)
{
    const float* query = (const float*)d_in[0];
    const float* value = (const float*)d_in[1];
    const float* keym  = (const float*)d_in[2];
    const float* vmem  = (const float*)d_in[3];
    const float* Wq    = (const float*)d_in[4];
    const float* bq    = (const float*)d_in[5];
    const float* Wv    = (const float*)d_in[6];
    const float* bv    = (const float*)d_in[7];
    const float* Wl    = (const float*)d_in[8];
    const float* bl    = (const float*)d_in[9];
    const float* g1    = (const float*)d_in[10];
    const float* b1    = (const float*)d_in[11];
    const float* g2    = (const float*)d_in[12];
    const float* b2    = (const float*)d_in[13];
    const float* g3    = (const float*)d_in[14];
    const float* b3    = (const float*)d_in[15];

    float* out    = (float*)d_out;
    float* out_te = out;
    float* out_tr = out + 8388608;
    float* out_rc = out + 16777216;    // 32 recon + 1 contrastive

    // Workspace layout (float offsets), round-14 (same as round-10..13).
    float* ws = (float*)d_ws;
    unsigned short* w_knb  = (unsigned short*)(ws + 0);
    unsigned short* w_vmTb = (unsigned short*)(ws + 32768);
    unsigned short* w_vnb  = (unsigned short*)(ws + 65536);
    float*          w_vn   = ws + 98304;
    unsigned short* w_w2tbf= (unsigned short*)(ws + 155648);
    unsigned short* w_vmbf = (unsigned short*)(ws + 385024);
    unsigned short* w_wlbf = (unsigned short*)(ws + 417792);
    unsigned short* w_xbf  = (unsigned short*)(ws + 1466368);
    unsigned short* w_kaddc= (unsigned short*)(ws + 5660672);
    unsigned short* w_vsb  = (unsigned short*)(ws + 13000704);
    unsigned short* w_qbf  = (unsigned short*)(ws + 14049280);
    unsigned short* w_vbf  = (unsigned short*)(ws + 18243584);
    unsigned short* w_wqbf = (unsigned short*)(ws + 22437888);
    unsigned short* w_wvbf = (unsigned short*)(ws + 22568960);

    // 1) all input conversions in one launch (+ vmbf pad zeros)
    conv_all<<<19008, 256, 0, stream>>>(query, value, Wq, Wv, Wl, vmem,
                                        w_qbf, w_vbf, w_wqbf, w_wvbf,
                                        w_wlbf, w_vmbf);
    // 2) input-only precomputes
    prep_key_norm<<<1024, 64, 0, stream>>>(keym, w_knb, out_rc);
    prep_value_norm<<<176, 256, 0, stream>>>(vmem, w_vn, w_vnb, w_vmTb);
    contrastive_kernel<<<112, 128, 0, stream>>>(w_vn, out_rc + 32);
    gemm_bf16<<<dim3(1, 4, 8), 256, 0, stream>>>(             // W2T bf16 direct
        (const short*)w_wlbf, HEADS * DIMC, (const short*)w_vmbf, DIMC,
        nullptr, w_w2tbf, HEADS * SLOTS, DIMC, nullptr, SLOTS,
        DIMC, 0, SLOTS);

    // 3) key addressing path
    gemm_bf16<<<dim3(4, 128), 256, 0, stream>>>(              // eqbf = q@Wq^T+bq
        (const short*)w_qbf, DIMC, (const short*)w_wqbf, DIMC,
        nullptr, w_xbf, DIMC, DIMC, bq, DIMC, 0, 0, 0);
    gemm_softmax<<<dim3(1, 128, 8), 256, 0, stream>>>(        // kaddc = softmax(sims)
        (const short*)w_xbf, DIMC, HD, (const short*)w_knb, HD, 128 * HD,
        HD, w_kaddc, HEADS * SLOTS, SLOTS, SLOTS);
    gemm_vir_te<<<NROWS / 64, 1024, 0, stream>>>(             // fused vir+LN+LN (64x512)
        (const short*)w_kaddc, HEADS * SLOTS, (const short*)w_w2tbf, HEADS * SLOTS,
        HEADS * SLOTS, bl, query, g1, b1, g2, b2, out_te);

    // 4) value addressing path
    gemm_bf16<<<dim3(4, 128), 256, 0, stream>>>(              // evbf = v@Wv^T+bv
        (const short*)w_vbf, DIMC, (const short*)w_wvbf, DIMC,
        nullptr, w_xbf, DIMC, DIMC, bv, DIMC, 0, 0, 0);
    gemm_softmax<<<dim3(1, 128, 1), 256, 0, stream>>>(        // vsb = softmax(ev@vn^T)
        (const short*)w_xbf, DIMC, 0, (const short*)w_vnb, DIMC, 0,
        DIMC, w_vsb, 128, 0, 128);
    gemm_aud_tr<<<NROWS / 32, 512, 0, stream>>>(              // fused aud+cos+LN+LN
        (const short*)w_vsb, 128, (const short*)w_vmTb, 128, 128,
        value, query, g1, b1, g3, b3, out_tr, out_rc);
}

// Round 12
// 329.922 us; speedup vs baseline: 1.0448x; 1.0448x over previous
//
#include <hip/hip_runtime.h>
#include <math.h>

// Problem constants
#define DIMC   512
#define HEADS  8
#define SLOTS  112
#define HD     64          // DIMC/HEADS
#define NROWS  16384       // B*S = 32*512
#define RADIUSF 16.0f

typedef short short8 __attribute__((ext_vector_type(8)));
typedef unsigned short ushort8 __attribute__((ext_vector_type(8)));
typedef float f32x4  __attribute__((ext_vector_type(4)));

__device__ __forceinline__ unsigned short f2bf(float f)
{
    unsigned u = __float_as_uint(f);
    unsigned r = (u + 0x7FFFu + ((u >> 16) & 1u)) >> 16;   // RNE
    return (unsigned short)r;
}
__device__ __forceinline__ float bf2f(unsigned short h)
{
    return __uint_as_float((unsigned)h << 16);
}

// Async global->LDS 16B/lane. LDS dest is wave-uniform base + lane*16.
__device__ __forceinline__ void gl16(const void* g, void* lds_wave_base)
{
    __builtin_amdgcn_global_load_lds(
        (const __attribute__((address_space(1))) unsigned int*)g,
        (__attribute__((address_space(3))) unsigned int*)lds_wave_base,
        16, 0, 0);
}

// ---------------------------------------------------------------------------
// DPP-based wave reductions (validated rounds 2-8). VALU-only, no LDS pipe.
// ---------------------------------------------------------------------------
#define DPP_ADD(x, ctrl, rmask)                                               \
    (x) += __int_as_float(__builtin_amdgcn_update_dpp(                        \
               0, __float_as_int(x), (ctrl), (rmask), 0xf, true))

__device__ __forceinline__ float wsum64(float x)
{
    DPP_ADD(x, 0x111, 0xf);
    DPP_ADD(x, 0x112, 0xf);
    DPP_ADD(x, 0x114, 0xf);
    DPP_ADD(x, 0x118, 0xf);
    DPP_ADD(x, 0x142, 0xa);
    DPP_ADD(x, 0x143, 0xc);
    return __int_as_float(__builtin_amdgcn_readlane(__float_as_int(x), 63));
}

__device__ __forceinline__ void wsum64_4(float& a, float& b, float& c, float& d)
{
    DPP_ADD(a, 0x111, 0xf); DPP_ADD(b, 0x111, 0xf); DPP_ADD(c, 0x111, 0xf); DPP_ADD(d, 0x111, 0xf);
    DPP_ADD(a, 0x112, 0xf); DPP_ADD(b, 0x112, 0xf); DPP_ADD(c, 0x112, 0xf); DPP_ADD(d, 0x112, 0xf);
    DPP_ADD(a, 0x114, 0xf); DPP_ADD(b, 0x114, 0xf); DPP_ADD(c, 0x114, 0xf); DPP_ADD(d, 0x114, 0xf);
    DPP_ADD(a, 0x118, 0xf); DPP_ADD(b, 0x118, 0xf); DPP_ADD(c, 0x118, 0xf); DPP_ADD(d, 0x118, 0xf);
    DPP_ADD(a, 0x142, 0xa); DPP_ADD(b, 0x142, 0xa); DPP_ADD(c, 0x142, 0xa); DPP_ADD(d, 0x142, 0xa);
    DPP_ADD(a, 0x143, 0xc); DPP_ADD(b, 0x143, 0xc); DPP_ADD(c, 0x143, 0xc); DPP_ADD(d, 0x143, 0xc);
    a = __int_as_float(__builtin_amdgcn_readlane(__float_as_int(a), 63));
    b = __int_as_float(__builtin_amdgcn_readlane(__float_as_int(b), 63));
    c = __int_as_float(__builtin_amdgcn_readlane(__float_as_int(c), 63));
    d = __int_as_float(__builtin_amdgcn_readlane(__float_as_int(d), 63));
}

// ---------------------------------------------------------------------------
// bf16 MFMA GEMM: C(MxN fp32) / Cb(MxN bf16) = A(MxK bf16) @ B(NxK bf16)^T
// (+ bias[col]). 128x128 tile, BK=32, gl16 staging (validated round 5/6).
// ---------------------------------------------------------------------------
__global__ __launch_bounds__(256)
void gemm_bf16(const short* __restrict__ A, int lda,
               const short* __restrict__ B, int ldb,
               float* __restrict__ C, unsigned short* __restrict__ Cb,
               int ldc, int K, const float* __restrict__ bias, int Nvalid,
               int aZ, int bZ, int cZ)
{
    __shared__ short As[128 * 32];
    __shared__ short Bs[128 * 32];
    A += (size_t)blockIdx.z * aZ;
    B += (size_t)blockIdx.z * bZ;
    const size_t czoff = (size_t)blockIdx.z * cZ;
    const int tid  = threadIdx.x;
    const int wave = tid >> 6;
    const int lane = tid & 63;
    const int m0 = blockIdx.y * 128;
    const int n0 = blockIdx.x * 128;
    const int wm = (wave >> 1) * 64;
    const int wn = (wave & 1) * 64;

    const int srow = tid >> 2;
    const int schk = (tid & 3) * 8;

    const int fr = lane & 15;
    const int fq = (lane >> 4) * 8;

    f32x4 acc[4][4] = {};

    const short* Ag = A + (size_t)(m0 + srow) * lda + schk;
    const short* Bg = B + (size_t)(n0 + srow) * ldb + schk;

    short* asL = As + wave * 512;
    short* asU = As + 2048 + wave * 512;
    short* bsL = Bs + wave * 512;
    short* bsU = Bs + 2048 + wave * 512;

    for (int k0 = 0; k0 < K; k0 += 32) {
        gl16(Ag, asL);
        gl16(Ag + (size_t)64 * lda, asU);
        gl16(Bg, bsL);
        gl16(Bg + (size_t)64 * ldb, bsU);
        Ag += 32; Bg += 32;
        __syncthreads();
        short8 af[4], bf[4];
        #pragma unroll
        for (int i = 0; i < 4; ++i)
            af[i] = *(const short8*)&As[(wm + i * 16 + fr) * 32 + fq];
        #pragma unroll
        for (int j = 0; j < 4; ++j)
            bf[j] = *(const short8*)&Bs[(wn + j * 16 + fr) * 32 + fq];
        #pragma unroll
        for (int i = 0; i < 4; ++i)
            #pragma unroll
            for (int j = 0; j < 4; ++j)
                acc[i][j] = __builtin_amdgcn_mfma_f32_16x16x32_bf16(
                    af[i], bf[j], acc[i][j], 0, 0, 0);
        __syncthreads();
    }

    const int cr = (lane >> 4) * 4;
    const int cc = lane & 15;
    #pragma unroll
    for (int i = 0; i < 4; ++i) {
        const int grow = m0 + wm + i * 16 + cr;
        #pragma unroll
        for (int j = 0; j < 4; ++j) {
            const int gcol = n0 + wn + j * 16 + cc;
            if (gcol < Nvalid) {
                const float bb = bias ? bias[gcol] : 0.f;
                const size_t base = czoff + (size_t)grow * ldc + gcol;
                #pragma unroll
                for (int r = 0; r < 4; ++r) {
                    const float val = acc[i][j][r] + bb;
                    if (C)  C[base + (size_t)r * ldc]  = val;
                    if (Cb) Cb[base + (size_t)r * ldc] = f2bf(val);
                }
            }
        }
    }
}

// ---------------------------------------------------------------------------
// Fused GEMM + in-kernel row-l2norm + row-softmax (validated round 6).
// ---------------------------------------------------------------------------
__global__ __launch_bounds__(256)
void gemm_softmax(const short* __restrict__ A, int lda, int aZ,
                  const short* __restrict__ B, int ldb, int bZ,
                  int K,
                  unsigned short* __restrict__ Ob, int ldo, int oPerZ, int padN)
{
    __shared__ short As[128 * 32];
    __shared__ short Bs[128 * 32];
    __shared__ float P[128][113];
    __shared__ float hinvS[128];
    A += (size_t)blockIdx.z * aZ;
    B += (size_t)blockIdx.z * bZ;
    const int tid  = threadIdx.x;
    const int wave = tid >> 6;
    const int lane = tid & 63;
    const int m0 = blockIdx.y * 128;
    const int wm = (wave >> 1) * 64;
    const int wn = (wave & 1) * 64;
    const int srow = tid >> 2;
    const int schk = (tid & 3) * 8;
    const int fr = lane & 15;
    const int fq = (lane >> 4) * 8;

    f32x4 acc[4][4] = {};
    float ss[4] = {0.f, 0.f, 0.f, 0.f};

    const short* Ag = A + (size_t)(m0 + srow) * lda + schk;
    const short* Bg = B + (size_t)srow * ldb + schk;

    short* asL = As + wave * 512;
    short* asU = As + 2048 + wave * 512;
    short* bsL = Bs + wave * 512;
    short* bsU = Bs + 2048 + wave * 512;

    for (int k0 = 0; k0 < K; k0 += 32) {
        gl16(Ag, asL);
        gl16(Ag + (size_t)64 * lda, asU);
        gl16(Bg, bsL);
        gl16(Bg + (size_t)64 * ldb, bsU);
        Ag += 32; Bg += 32;
        __syncthreads();
        short8 af[4], bf[4];
        #pragma unroll
        for (int i = 0; i < 4; ++i)
            af[i] = *(const short8*)&As[(wm + i * 16 + fr) * 32 + fq];
        #pragma unroll
        for (int j = 0; j < 4; ++j)
            bf[j] = *(const short8*)&Bs[(wn + j * 16 + fr) * 32 + fq];
        #pragma unroll
        for (int i = 0; i < 4; ++i)
            #pragma unroll
            for (int e = 0; e < 8; ++e) {
                const float f = bf2f((unsigned short)af[i][e]);
                ss[i] += f * f;
            }
        #pragma unroll
        for (int i = 0; i < 4; ++i)
            #pragma unroll
            for (int j = 0; j < 4; ++j)
                acc[i][j] = __builtin_amdgcn_mfma_f32_16x16x32_bf16(
                    af[i], bf[j], acc[i][j], 0, 0, 0);
        __syncthreads();
    }

    #pragma unroll
    for (int i = 0; i < 4; ++i) {
        ss[i] += __shfl_xor(ss[i], 16, 64);
        ss[i] += __shfl_xor(ss[i], 32, 64);
    }
    if (lane < 16) {
        #pragma unroll
        for (int i = 0; i < 4; ++i)
            hinvS[wm + i * 16 + lane] = 1.f / fmaxf(sqrtf(ss[i]), 1e-12f);
    }

    const int cr = (lane >> 4) * 4;
    const int cc = lane & 15;
    #pragma unroll
    for (int i = 0; i < 4; ++i) {
        const int prow = wm + i * 16 + cr;
        #pragma unroll
        for (int j = 0; j < 4; ++j) {
            const int pcol = wn + j * 16 + cc;
            if (pcol < SLOTS) {
                #pragma unroll
                for (int r = 0; r < 4; ++r)
                    P[prow + r][pcol] = acc[i][j][r];
            }
        }
    }
    __syncthreads();

    const int rowt = tid >> 1;
    const int half = tid & 1;
    const int k0 = half * 56;
    const int rr = m0 + rowt;
    const float s = RADIUSF * hinvS[rowt];
    float mx = -1e30f;
    for (int k = k0; k < k0 + 56; ++k) mx = fmaxf(mx, P[rowt][k]);
    mx = fmaxf(mx, __shfl_xor(mx, 1, 64));
    float sum = 0.f;
    for (int k = k0; k < k0 + 56; ++k) {
        const float e = __expf(s * (P[rowt][k] - mx));
        P[rowt][k] = e;
        sum += e;
    }
    sum += __shfl_xor(sum, 1, 64);
    const float inv = 1.f / sum;
    unsigned short* orow = Ob + (size_t)rr * ldo + (size_t)blockIdx.z * oPerZ;
    for (int k = k0; k < k0 + 56; ++k) orow[k] = f2bf(P[rowt][k] * inv);
    if (half == 1)
        for (int k = SLOTS; k < padN; ++k) orow[k] = 0;
}

// ---------------------------------------------------------------------------
// Round-11/15 fused GEMM (32x512 tile) + LN epilogue — the round-8 form,
// REVERTED to after both M=64 variants regressed:
//   round-9  (512 thr, 85 KB):  2 waves/SIMD -> 51.5 µs (occupancy-bound)
//   round-11 (1024 thr, 74 KB): 16-wave barriers + LDS contention, no
//                               co-resident block -> 56-57 µs
// This 8-wave 2-blocks/CU structure measured 39.9 µs (system 328.9 µs):
// inter-block overlap beats both larger-tile variants. Keeping it.
// ---------------------------------------------------------------------------
#define FUSED_LDS_DECL                                                        \
    __shared__ float U[17408];  /* 69632 B: staging (68 KB) ∪ P (64.5 KB) */  \
    float* P = U;                                                             \
    short* As0 = (short*)U;          /* [32][32] chunk 0 */                   \
    short* As1 = As0 + 1024;         /* [32][32] chunk 1 */                   \
    short* Bs0 = As1 + 1024;         /* [512][32] chunk 0 */                  \
    short* Bs1 = Bs0 + 16384;        /* [512][32] chunk 1 */

#define FUSED_GEMM_CORE(Aptr, lda, Bptr, ldb, K)                              \
    f32x4 acc[2][4] = {};                                                     \
    {                                                                         \
        const int lrow = lane >> 2;                                           \
        const int lchk = (lane & 3) * 8;                                      \
        for (int k0 = 0; k0 < (K); k0 += 64) {                                \
            if (wave < 2)                                                     \
                gl16((Aptr) + (size_t)(m0 + wave * 16 + lrow) * (lda) + k0 + lchk, \
                     As0 + wave * 512);                                       \
            else if (wave < 4)                                                \
                gl16((Aptr) + (size_t)(m0 + (wave - 2) * 16 + lrow) * (lda) + k0 + 32 + lchk, \
                     As1 + (wave - 2) * 512);                                 \
            _Pragma("unroll")                                                 \
            for (int s = 0; s < 4; ++s) {                                     \
                const size_t brow = (size_t)(wave * 64 + s * 16 + lrow);      \
                gl16((Bptr) + brow * (ldb) + k0 + lchk,                       \
                     Bs0 + (wave * 64 + s * 16) * 32);                        \
                gl16((Bptr) + brow * (ldb) + k0 + 32 + lchk,                  \
                     Bs1 + (wave * 64 + s * 16) * 32);                        \
            }                                                                 \
            __syncthreads();                                                  \
            short8 af0[2], af1[2], bf0[4], bf1[4];                            \
            _Pragma("unroll")                                                 \
            for (int i = 0; i < 2; ++i) {                                     \
                af0[i] = *(const short8*)&As0[(i * 16 + fr) * 32 + fq];       \
                af1[i] = *(const short8*)&As1[(i * 16 + fr) * 32 + fq];       \
            }                                                                 \
            _Pragma("unroll")                                                 \
            for (int c = 0; c < 4; ++c) {                                     \
                bf0[c] = *(const short8*)&Bs0[(wave * 64 + c * 16 + fr) * 32 + fq]; \
                bf1[c] = *(const short8*)&Bs1[(wave * 64 + c * 16 + fr) * 32 + fq]; \
            }                                                                 \
            _Pragma("unroll")                                                 \
            for (int i = 0; i < 2; ++i)                                       \
                _Pragma("unroll")                                             \
                for (int c = 0; c < 4; ++c) {                                 \
                    acc[i][c] = __builtin_amdgcn_mfma_f32_16x16x32_bf16(      \
                        af0[i], bf0[c], acc[i][c], 0, 0, 0);                  \
                    acc[i][c] = __builtin_amdgcn_mfma_f32_16x16x32_bf16(      \
                        af1[i], bf1[c], acc[i][c], 0, 0, 0);                  \
                }                                                             \
            __syncthreads();                                                  \
        }                                                                     \
    }                                                                         \
    {                                                                         \
        const int cr = (lane >> 4) * 4;                                       \
        const int cc = lane & 15;                                             \
        _Pragma("unroll")                                                     \
        for (int i = 0; i < 2; ++i)                                           \
            _Pragma("unroll")                                                 \
            for (int c = 0; c < 4; ++c) {                                     \
                const int col = wave * 64 + c * 16 + cc;                      \
                _Pragma("unroll")                                             \
                for (int r = 0; r < 4; ++r)                                   \
                    P[(i * 16 + cr + r) * 516 + col] = acc[i][c][r];          \
            }                                                                 \
    }                                                                         \
    __syncthreads();

// vir path: x = A@B^T + bl -> LN(g2,b2) -> +query -> LN(g1,b1) -> out_te
__global__ __launch_bounds__(512, 4)
void gemm_vir_te(const short* __restrict__ A, int lda,
                 const short* __restrict__ B, int ldb, int K,
                 const float* __restrict__ bias, const float* __restrict__ query,
                 const float* __restrict__ g1, const float* __restrict__ b1,
                 const float* __restrict__ g2, const float* __restrict__ b2,
                 float* __restrict__ out_te)
{
    FUSED_LDS_DECL
    const int tid = threadIdx.x;
    const int wave = tid >> 6;
    const int lane = tid & 63;
    const int m0 = blockIdx.x * 32;
    const int fr = lane & 15;
    const int fq = (lane >> 4) * 8;

    FUSED_GEMM_CORE(A, lda, B, ldb, K)

    const int c0 = lane * 8;
    float blv[8], gg2[8], bb2[8], gg1[8], bb1[8];
    *(f32x4*)&blv[0] = *(const f32x4*)(bias + c0);
    *(f32x4*)&blv[4] = *(const f32x4*)(bias + c0 + 4);
    *(f32x4*)&gg2[0] = *(const f32x4*)(g2 + c0);
    *(f32x4*)&gg2[4] = *(const f32x4*)(g2 + c0 + 4);
    *(f32x4*)&bb2[0] = *(const f32x4*)(b2 + c0);
    *(f32x4*)&bb2[4] = *(const f32x4*)(b2 + c0 + 4);
    *(f32x4*)&gg1[0] = *(const f32x4*)(g1 + c0);
    *(f32x4*)&gg1[4] = *(const f32x4*)(g1 + c0 + 4);
    *(f32x4*)&bb1[0] = *(const f32x4*)(b1 + c0);
    *(f32x4*)&bb1[4] = *(const f32x4*)(b1 + c0 + 4);

    // 8 waves x 4 rows each; two 2-row passes per wave.
    for (int rp = 0; rp < 2; ++rp) {
        const int lr0 = wave * 4 + rp * 2;
        float x[2][8], q[2][8];
        #pragma unroll
        for (int p = 0; p < 2; ++p) {
            *(f32x4*)&x[p][0] = *(const f32x4*)&P[(lr0 + p) * 516 + c0];
            *(f32x4*)&x[p][4] = *(const f32x4*)&P[(lr0 + p) * 516 + c0 + 4];
            const size_t gbase = (size_t)(m0 + lr0 + p) * DIMC + c0;
            *(f32x4*)&q[p][0] = *(const f32x4*)(query + gbase);
            *(f32x4*)&q[p][4] = *(const f32x4*)(query + gbase + 4);
            #pragma unroll
            for (int j = 0; j < 8; ++j) x[p][j] += blv[j];
        }
        float s1[2] = {0.f, 0.f}, s2[2] = {0.f, 0.f};
        #pragma unroll
        for (int p = 0; p < 2; ++p)
            #pragma unroll
            for (int j = 0; j < 8; ++j) {
                s1[p] += x[p][j];
                s2[p] += x[p][j] * x[p][j];
            }
        wsum64_4(s1[0], s2[0], s1[1], s2[1]);

        float y[2][8];
        float t1[2] = {0.f, 0.f}, t2[2] = {0.f, 0.f};
        #pragma unroll
        for (int p = 0; p < 2; ++p) {
            const float mu = s1[p] * (1.f / DIMC);
            const float var = s2[p] * (1.f / DIMC) - mu * mu;
            const float rstd = rsqrtf(var + 1e-5f);
            #pragma unroll
            for (int j = 0; j < 8; ++j) {
                const float v = (x[p][j] - mu) * rstd * gg2[j] + bb2[j];
                y[p][j] = q[p][j] + v;
                t1[p] += y[p][j];
                t2[p] += y[p][j] * y[p][j];
            }
        }
        wsum64_4(t1[0], t2[0], t1[1], t2[1]);

        #pragma unroll
        for (int p = 0; p < 2; ++p) {
            const float mu = t1[p] * (1.f / DIMC);
            const float var = t2[p] * (1.f / DIMC) - mu * mu;
            const float rstd = rsqrtf(var + 1e-5f);
            float o[8];
            #pragma unroll
            for (int j = 0; j < 8; ++j)
                o[j] = (y[p][j] - mu) * rstd * gg1[j] + bb1[j];
            const size_t gbase = (size_t)(m0 + lr0 + p) * DIMC + c0;
            *(float4*)(out_te + gbase)     = make_float4(o[0], o[1], o[2], o[3]);
            *(float4*)(out_te + gbase + 4) = make_float4(o[4], o[5], o[6], o[7]);
        }
    }
}

// aud path: a = A@B^T -> cos/recon vs value -> LN(g3,b3) -> +query ->
// LN(g1,b1) -> out_tr (+ one recon atomic per block; 32 | 512).
__global__ __launch_bounds__(512, 4)
void gemm_aud_tr(const short* __restrict__ A, int lda,
                 const short* __restrict__ B, int ldb, int K,
                 const float* __restrict__ value, const float* __restrict__ query,
                 const float* __restrict__ g1, const float* __restrict__ b1,
                 const float* __restrict__ g3, const float* __restrict__ b3,
                 float* __restrict__ out_tr, float* __restrict__ recon)
{
    FUSED_LDS_DECL
    __shared__ float red[8];
    const int tid = threadIdx.x;
    const int wave = tid >> 6;
    const int lane = tid & 63;
    const int m0 = blockIdx.x * 32;
    const int fr = lane & 15;
    const int fq = (lane >> 4) * 8;

    FUSED_GEMM_CORE(A, lda, B, ldb, K)

    const int c0 = lane * 8;
    float gg3[8], bb3[8], gg1[8], bb1[8];
    *(f32x4*)&gg3[0] = *(const f32x4*)(g3 + c0);
    *(f32x4*)&gg3[4] = *(const f32x4*)(g3 + c0 + 4);
    *(f32x4*)&bb3[0] = *(const f32x4*)(b3 + c0);
    *(f32x4*)&bb3[4] = *(const f32x4*)(b3 + c0 + 4);
    *(f32x4*)&gg1[0] = *(const f32x4*)(g1 + c0);
    *(f32x4*)&gg1[4] = *(const f32x4*)(g1 + c0 + 4);
    *(f32x4*)&bb1[0] = *(const f32x4*)(b1 + c0);
    *(f32x4*)&bb1[4] = *(const f32x4*)(b1 + c0 + 4);

    float rloc = 0.f;
    for (int rp = 0; rp < 2; ++rp) {
        const int lr0 = wave * 4 + rp * 2;
        float a[2][8], v[2][8], q[2][8];
        #pragma unroll
        for (int p = 0; p < 2; ++p) {
            *(f32x4*)&a[p][0] = *(const f32x4*)&P[(lr0 + p) * 516 + c0];
            *(f32x4*)&a[p][4] = *(const f32x4*)&P[(lr0 + p) * 516 + c0 + 4];
            const size_t gbase = (size_t)(m0 + lr0 + p) * DIMC + c0;
            *(f32x4*)&v[p][0] = *(const f32x4*)(value + gbase);
            *(f32x4*)&v[p][4] = *(const f32x4*)(value + gbase + 4);
            *(f32x4*)&q[p][0] = *(const f32x4*)(query + gbase);
            *(f32x4*)&q[p][4] = *(const f32x4*)(query + gbase + 4);
        }
        float dot[2] = {0.f, 0.f}, na[2] = {0.f, 0.f};
        float nv[2] = {0.f, 0.f}, s1[2] = {0.f, 0.f};
        #pragma unroll
        for (int p = 0; p < 2; ++p)
            #pragma unroll
            for (int j = 0; j < 8; ++j) {
                dot[p] += a[p][j] * v[p][j];
                na[p]  += a[p][j] * a[p][j];
                nv[p]  += v[p][j] * v[p][j];
                s1[p]  += a[p][j];
            }
        wsum64_4(dot[0], na[0], nv[0], s1[0]);
        wsum64_4(dot[1], na[1], nv[1], s1[1]);

        #pragma unroll
        for (int p = 0; p < 2; ++p) {
            const float cosv = dot[p] / fmaxf(sqrtf(na[p]) * sqrtf(nv[p]), 1e-8f);
            rloc += fabsf(1.f - cosv);
        }

        float y[2][8];
        float t1[2] = {0.f, 0.f}, t2[2] = {0.f, 0.f};
        #pragma unroll
        for (int p = 0; p < 2; ++p) {
            const float mu = s1[p] * (1.f / DIMC);
            const float var = na[p] * (1.f / DIMC) - mu * mu;   // na == sum(a^2)
            const float rstd = rsqrtf(var + 1e-5f);
            #pragma unroll
            for (int j = 0; j < 8; ++j) {
                const float w = (a[p][j] - mu) * rstd * gg3[j] + bb3[j];
                y[p][j] = q[p][j] + w;
                t1[p] += y[p][j];
                t2[p] += y[p][j] * y[p][j];
            }
        }
        wsum64_4(t1[0], t2[0], t1[1], t2[1]);

        #pragma unroll
        for (int p = 0; p < 2; ++p) {
            const float mu = t1[p] * (1.f / DIMC);
            const float var = t2[p] * (1.f / DIMC) - mu * mu;
            const float rstd = rsqrtf(var + 1e-5f);
            float o[8];
            #pragma unroll
            for (int j = 0; j < 8; ++j)
                o[j] = (y[p][j] - mu) * rstd * gg1[j] + bb1[j];
            const size_t gbase = (size_t)(m0 + lr0 + p) * DIMC + c0;
            *(float4*)(out_tr + gbase)     = make_float4(o[0], o[1], o[2], o[3]);
            *(float4*)(out_tr + gbase + 4) = make_float4(o[4], o[5], o[6], o[7]);
        }
    }

    if (lane == 0) red[wave] = rloc;
    __syncthreads();
    if (tid == 0)
        atomicAdd(&recon[m0 >> 9], red[0] + red[1] + red[2] + red[3]
                                 + red[4] + red[5] + red[6] + red[7]);
}

// ---------------------------------------------------------------------------
// Small helpers (all validated round 6)
// ---------------------------------------------------------------------------
__device__ __forceinline__ float block_sum_256(float v, float* red)
{
    #pragma unroll
    for (int off = 32; off; off >>= 1) v += __shfl_down(v, off, 64);
    const int lane = threadIdx.x & 63, wid = threadIdx.x >> 6;
    __syncthreads();
    if (lane == 0) red[wid] = v;
    __syncthreads();
    return red[0] + red[1] + red[2] + red[3];
}

__global__ void conv_all(const float* __restrict__ q, const float* __restrict__ v,
                         const float* __restrict__ Wq, const float* __restrict__ Wv,
                         const float* __restrict__ Wl, const float* __restrict__ vm,
                         unsigned short* __restrict__ qbf, unsigned short* __restrict__ vbf,
                         unsigned short* __restrict__ wqbf, unsigned short* __restrict__ wvbf,
                         unsigned short* __restrict__ wlbf, unsigned short* __restrict__ vmbf)
{
    const int i = blockIdx.x * blockDim.x + threadIdx.x;   // float4-unit index
    const float* src;
    unsigned short* dst;
    int off;
    if (i < 2097152)      { src = q;  dst = qbf;  off = i; }
    else if (i < 4194304) { src = v;  dst = vbf;  off = i - 2097152; }
    else if (i < 4259840) { src = Wq; dst = wqbf; off = i - 4194304; }
    else if (i < 4325376) { src = Wv; dst = wvbf; off = i - 4259840; }
    else if (i < 4849664) { src = Wl; dst = wlbf; off = i - 4325376; }
    else if (i < 4864000) { src = vm; dst = vmbf; off = i - 4849664; }
    else {                 // zero vmbf pad rows 112..127 (8192 bf16)
        const int j = i - 4864000;   // 0..2047
        *(ushort4*)(vmbf + 57344 + (size_t)j * 4) = make_ushort4(0, 0, 0, 0);
        return;
    }
    const float4 x = *(const float4*)(src + (size_t)off * 4);
    ushort4 o;
    o.x = f2bf(x.x); o.y = f2bf(x.y); o.z = f2bf(x.z); o.w = f2bf(x.w);
    *(ushort4*)(dst + (size_t)off * 4) = o;
}

__global__ void prep_key_norm(const float* __restrict__ km,
                              unsigned short* __restrict__ knb,
                              float* __restrict__ outrc)
{
    const int row = blockIdx.x;         // h*128+s
    const int h = row >> 7, s = row & 127;
    const int lane = threadIdx.x;       // 64 threads
    if (row == 0 && lane < 33) outrc[lane] = 0.f;
    const float v = (s < SLOTS) ? km[(size_t)(h * SLOTS + s) * HD + lane] : 0.f;
    const float ssum = wsum64(v * v);
    const float inv = 1.f / fmaxf(sqrtf(ssum), 1e-12f);
    knb[(size_t)row * HD + lane] = f2bf(v * inv);
}

__global__ void prep_value_norm(const float* __restrict__ vm,
                                float* __restrict__ vn,
                                unsigned short* __restrict__ vnb,
                                unsigned short* __restrict__ vmTb)
{
    const int row = blockIdx.x;        // 0..175
    const int tid = threadIdx.x;       // 256
    if (row >= 112) {
        const int idx = (row - 112) * 256 + tid;   // 0..16383
        if (idx < 8192) {
            vmTb[(size_t)(idx >> 4) * 128 + 112 + (idx & 15)] = 0;
        } else {
            const int j = idx - 8192;
            vnb[(size_t)(112 + (j >> 9)) * 512 + (j & 511)] = 0;
        }
        return;
    }
    __shared__ float red[4];
    const float v0 = vm[(size_t)row * DIMC + tid];
    const float v1 = vm[(size_t)row * DIMC + 256 + tid];
    const float tot = block_sum_256(v0 * v0 + v1 * v1, red);
    const float inv = 1.f / fmaxf(sqrtf(tot), 1e-12f);
    vn[(size_t)row * DIMC + tid]        = v0 * inv;
    vn[(size_t)row * DIMC + 256 + tid]  = v1 * inv;
    vnb[(size_t)row * DIMC + tid]       = f2bf(v0 * inv);
    vnb[(size_t)row * DIMC + 256 + tid] = f2bf(v1 * inv);
    vmTb[(size_t)tid * 128 + row]         = f2bf(v0);
    vmTb[(size_t)(256 + tid) * 128 + row] = f2bf(v1);
}

__global__ void contrastive_kernel(const float* __restrict__ vn, float* __restrict__ outc)
{
    __shared__ float vni[DIMC];
    __shared__ float red[2];
    const int i = blockIdx.x, tid = threadIdx.x;   // 128 threads
    for (int d = tid; d < DIMC; d += 128) vni[d] = vn[(size_t)i * DIMC + d];
    __syncthreads();
    float t = 0.f;
    if (tid < SLOTS) {
        const float* r = vn + (size_t)tid * DIMC;
        float dot = 0.f;
        for (int d = 0; d < DIMC; ++d) dot += vni[d] * r[d];
        const float delta = (tid == i) ? 1.f : 0.f;
        t = fabsf(delta - dot);
    }
    #pragma unroll
    for (int off = 32; off; off >>= 1) t += __shfl_down(t, off, 64);
    if ((tid & 63) == 0) red[tid >> 6] = t;
    __syncthreads();
    if (tid == 0) atomicAdd(outc, 0.5f * (red[0] + red[1]));
}

// ---------------------------------------------------------------------------
// Launch
// ---------------------------------------------------------------------------
extern "C" void kernel_launch(void* const* d_in, const int* in_sizes, int n_in,
                              void* d_out, int out_size, void* d_ws, size_t ws_size,
                              hipStream_t stream)
{
    const float* query = (const float*)d_in[0];
    const float* value = (const float*)d_in[1];
    const float* keym  = (const float*)d_in[2];
    const float* vmem  = (const float*)d_in[3];
    const float* Wq    = (const float*)d_in[4];
    const float* bq    = (const float*)d_in[5];
    const float* Wv    = (const float*)d_in[6];
    const float* bv    = (const float*)d_in[7];
    const float* Wl    = (const float*)d_in[8];
    const float* bl    = (const float*)d_in[9];
    const float* g1    = (const float*)d_in[10];
    const float* b1    = (const float*)d_in[11];
    const float* g2    = (const float*)d_in[12];
    const float* b2    = (const float*)d_in[13];
    const float* g3    = (const float*)d_in[14];
    const float* b3    = (const float*)d_in[15];

    float* out    = (float*)d_out;
    float* out_te = out;
    float* out_tr = out + 8388608;
    float* out_rc = out + 16777216;    // 32 recon + 1 contrastive

    // Workspace layout (float offsets), round-15 (= round-8/10 layout).
    float* ws = (float*)d_ws;
    unsigned short* w_knb  = (unsigned short*)(ws + 0);
    unsigned short* w_vmTb = (unsigned short*)(ws + 32768);
    unsigned short* w_vnb  = (unsigned short*)(ws + 65536);
    float*          w_vn   = ws + 98304;
    unsigned short* w_w2tbf= (unsigned short*)(ws + 155648);
    unsigned short* w_vmbf = (unsigned short*)(ws + 385024);
    unsigned short* w_wlbf = (unsigned short*)(ws + 417792);
    unsigned short* w_xbf  = (unsigned short*)(ws + 1466368);
    unsigned short* w_kaddc= (unsigned short*)(ws + 5660672);
    unsigned short* w_vsb  = (unsigned short*)(ws + 13000704);
    unsigned short* w_qbf  = (unsigned short*)(ws + 14049280);
    unsigned short* w_vbf  = (unsigned short*)(ws + 18243584);
    unsigned short* w_wqbf = (unsigned short*)(ws + 22437888);
    unsigned short* w_wvbf = (unsigned short*)(ws + 22568960);

    // 1) all input conversions in one launch (+ vmbf pad zeros)
    conv_all<<<19008, 256, 0, stream>>>(query, value, Wq, Wv, Wl, vmem,
                                        w_qbf, w_vbf, w_wqbf, w_wvbf,
                                        w_wlbf, w_vmbf);
    // 2) input-only precomputes
    prep_key_norm<<<1024, 64, 0, stream>>>(keym, w_knb, out_rc);
    prep_value_norm<<<176, 256, 0, stream>>>(vmem, w_vn, w_vnb, w_vmTb);
    contrastive_kernel<<<112, 128, 0, stream>>>(w_vn, out_rc + 32);
    gemm_bf16<<<dim3(1, 4, 8), 256, 0, stream>>>(             // W2T bf16 direct
        (const short*)w_wlbf, HEADS * DIMC, (const short*)w_vmbf, DIMC,
        nullptr, w_w2tbf, HEADS * SLOTS, DIMC, nullptr, SLOTS,
        DIMC, 0, SLOTS);

    // 3) key addressing path
    gemm_bf16<<<dim3(4, 128), 256, 0, stream>>>(              // eqbf = q@Wq^T+bq
        (const short*)w_qbf, DIMC, (const short*)w_wqbf, DIMC,
        nullptr, w_xbf, DIMC, DIMC, bq, DIMC, 0, 0, 0);
    gemm_softmax<<<dim3(1, 128, 8), 256, 0, stream>>>(        // kaddc = softmax(sims)
        (const short*)w_xbf, DIMC, HD, (const short*)w_knb, HD, 128 * HD,
        HD, w_kaddc, HEADS * SLOTS, SLOTS, SLOTS);
    gemm_vir_te<<<NROWS / 32, 512, 0, stream>>>(              // fused vir+LN+LN
        (const short*)w_kaddc, HEADS * SLOTS, (const short*)w_w2tbf, HEADS * SLOTS,
        HEADS * SLOTS, bl, query, g1, b1, g2, b2, out_te);

    // 4) value addressing path
    gemm_bf16<<<dim3(4, 128), 256, 0, stream>>>(              // evbf = v@Wv^T+bv
        (const short*)w_vbf, DIMC, (const short*)w_wvbf, DIMC,
        nullptr, w_xbf, DIMC, DIMC, bv, DIMC, 0, 0, 0);
    gemm_softmax<<<dim3(1, 128, 1), 256, 0, stream>>>(        // vsb = softmax(ev@vn^T)
        (const short*)w_xbf, DIMC, 0, (const short*)w_vnb, DIMC, 0,
        DIMC, w_vsb, 128, 0, 128);
    gemm_aud_tr<<<NROWS / 32, 512, 0, stream>>>(              // fused aud+cos+LN+LN
        (const short*)w_vsb, 128, (const short*)w_vmTb, 128, 128,
        value, query, g1, b1, g3, b3, out_tr, out_rc);
}